// Round 1
// 5573.838 us; speedup vs baseline: 1.1536x; 1.1536x over previous
//
#include <hip/hip_runtime.h>
#include <math.h>

#define B    128
#define T    20
#define TD   19      // Tdec
#define V    10000
#define D    1024
#define E    1024
#define A_DIM 1024
#define F    2048
#define NR   36
#define BD   (B * D)  // 131072

typedef __attribute__((ext_vector_type(8))) short bf16x8;
typedef __attribute__((ext_vector_type(4))) float f32x4;

__device__ __forceinline__ float sigm(float x) { return 1.f / (1.f + __expf(-x)); }

__device__ __forceinline__ unsigned short f2bf(float f) {
    union { float f; unsigned u; } x; x.f = f;
    unsigned r = x.u + 0x7fffu + ((x.u >> 16) & 1u);
    return (unsigned short)(r >> 16);
}
__device__ __forceinline__ float bf2f(unsigned short u) {
    union { float f; unsigned u; } x; x.u = ((unsigned)u) << 16; return x.f;
}
__device__ __forceinline__ uint4 pack8(const float* __restrict__ src) {
    float4 a = *(const float4*)src, b = *(const float4*)(src + 4);
    union { unsigned short u[8]; uint4 v; } p;
    p.u[0] = f2bf(a.x); p.u[1] = f2bf(a.y); p.u[2] = f2bf(a.z); p.u[3] = f2bf(a.w);
    p.u[4] = f2bf(b.x); p.u[5] = f2bf(b.y); p.u[6] = f2bf(b.z); p.u[7] = f2bf(b.w);
    return p.v;
}

// ---------------------------------------------------------------------------
// Sort (stable descending by sizes), seqs/order outputs, active counts
// ---------------------------------------------------------------------------
__global__ void k_sort_init(const int* __restrict__ sizes,
                            const int* __restrict__ sequences,
                            int* __restrict__ order,
                            int* __restrict__ active,
                            int* __restrict__ seqs_s,
                            float* __restrict__ out)
{
    int tid = threadIdx.x;                // 128 threads
    __shared__ int s_sizes[B];
    __shared__ int s_dl[B];
    s_sizes[tid] = sizes[tid];
    __syncthreads();
    int si = s_sizes[tid];
    int rank = 0;
    for (int j = 0; j < B; ++j) {
        int sj = s_sizes[j];
        if (sj > si || (sj == si && j < tid)) rank++;
    }
    order[rank] = tid;
    __syncthreads();
    int ob = order[tid];
    int dl = s_sizes[ob] - 1;
    s_dl[tid] = dl;
    for (int tt = 0; tt < T; ++tt) {
        int sq = sequences[ob * T + tt];
        seqs_s[tid * T + tt] = sq;
        out[(size_t)B * TD * V + tid * T + tt] = (float)sq;
    }
    out[(size_t)B * TD * V + B * T + tid] = (float)ob;
    __syncthreads();
    if (tid < TD) {
        int c = 0;
        for (int b = 0; b < B; ++b) c += (s_dl[b] > tid) ? 1 : 0;
        active[tid] = c;
    }
    if (tid == 0) out[(size_t)B * TD * V + B * T + B] = 0.f;   // loss accumulator
}

__global__ void k_zero(float* __restrict__ p, int n) {
    int i = blockIdx.x * 256 + threadIdx.x;
    if (i < n) p[i] = 0.f;
}

// weight f32 -> bf16, rows concatenated [s1 row (K1) | s2 row (K2)]
// s2 == nullptr with K2 > 0: zero-pad the K2 region.
__global__ void k_w2bf(const float* __restrict__ s1, int K1,
                       const float* __restrict__ s2, int K2,
                       unsigned short* __restrict__ dst, long total /*granules*/)
{
    long g = (long)blockIdx.x * 256 + threadIdx.x;
    if (g >= total) return;
    int Kt = K1 + K2;
    int gpr = Kt >> 3;
    int row = (int)(g / gpr);
    int k8 = (int)(g % gpr) << 3;
    if (k8 >= K1 && !s2) {
        uint4 z{};
        *(uint4*)(dst + ((size_t)g << 3)) = z;
        return;
    }
    const float* src = (k8 < K1) ? (s1 + (size_t)row * K1 + k8)
                                 : (s2 + (size_t)row * K2 + (k8 - K1));
    *(uint4*)(dst + ((size_t)g << 3)) = pack8(src);
}

// feats (sorted by order) -> bf16 [4608 x 2048]
__global__ void k_feats2bf(const float* __restrict__ feats, const int* __restrict__ order,
                           unsigned short* __restrict__ dst)
{
    long g = (long)blockIdx.x * 256 + threadIdx.x;   // 4608*256 granules
    int row = (int)(g >> 8);
    int k8 = ((int)g & 255) << 3;
    int b = row / NR, r = row - b * NR;
    const float* src = feats + ((size_t)order[b] * NR + r) * F + k8;
    *(uint4*)(dst + (size_t)row * F + k8) = pack8(src);
}

// featsAvg -> bf16 directly into xtd slot [1024,3072)
__global__ void k_favg(const float* __restrict__ feats, const int* __restrict__ order,
                       unsigned short* __restrict__ xtd)
{
    int idx = blockIdx.x * 256 + threadIdx.x;   // B*F = 262144
    int b = idx >> 11, f = idx & 2047;
    const float* base = feats + (size_t)order[b] * NR * F + f;
    float s = 0.f;
#pragma unroll
    for (int r = 0; r < NR; ++r) s += base[(size_t)r * F];
    xtd[(size_t)b * 5120 + 1024 + f] = f2bf(s * (1.f / NR));
}

// embeddings (sorted) -> bf16 [B x TD x 1024]
__global__ void k_emb2bf(const float* __restrict__ emb, const int* __restrict__ seqs_s,
                         unsigned short* __restrict__ embs_bf)
{
    long g = (long)blockIdx.x * 256 + threadIdx.x;  // B*TD*128 granules
    if (g >= (long)B * TD * 128) return;
    int b = (int)(g / (TD * 128));
    int rem = (int)(g - (long)b * (TD * 128));
    int t = rem >> 7, e8 = (rem & 127) << 3;
    const float* src = emb + (size_t)seqs_s[b * T + t] * E + e8;
    *(uint4*)(embs_bf + (((size_t)(b * TD + t)) << 10) + e8) = pack8(src);
}

// copy embs_bf[:,t,:] into xtd emb slot [3072,4096)  (used once, t=0)
__global__ void k_embslot(const unsigned short* __restrict__ embs_bf,
                          unsigned short* __restrict__ xtd, int t)
{
    int g = blockIdx.x * 256 + threadIdx.x;  // B*128 = 16384
    int b = g >> 7, e8 = (g & 127) << 3;
    *(uint4*)(xtd + (size_t)b * 5120 + 3072 + e8) =
        *(const uint4*)(embs_bf + (((size_t)(b * TD + t)) << 10) + e8);
}

// combined bias for [War | Wad] GEMM: cols<4096: ar_bi+ar_bh ; else ad_b
__global__ void k_biascomb(const float* __restrict__ ar_bi, const float* __restrict__ ar_bh,
                           const float* __restrict__ ad_b, float* __restrict__ dst)
{
    int i = blockIdx.x * 256 + threadIdx.x;   // 5120
    dst[i] = (i < 4096) ? ar_bi[i] + ar_bh[i] : ad_b[i - 4096];
}

// ---------------------------------------------------------------------------
// MFMA bf16 GEMM: C[m][n] = sum_k A[m][k]*W[n][k] (+bias (+bias2))
//   Tile M=128 x N=32, BK=64, 256 threads (4 waves).
//   modes: 0 plain store;
//          1 batched ARNet loss (no store): per blockIdx.y (= t-1) active
//            count actp[blockIdx.y]; sum (acc+bias-sub)^2 over (row&127)<act
//            -> atomicAdd(lossp, *0.005/act);
//          2 store, zero rows>=*actp (legacy);
//          3 batched pred store: row = t*128+b, write out[b][t][col],
//            zero if b >= actp[t].
// ---------------------------------------------------------------------------
__global__ __launch_bounds__(256)
void k_gemm(const unsigned short* __restrict__ A, int lda,
            const unsigned short* __restrict__ W, int K,
            const float* __restrict__ bias, const float* __restrict__ bias2,
            float* __restrict__ C, int ldc, int N,
            int mode, const float* __restrict__ sub, const int* __restrict__ actp,
            float* __restrict__ lossp)
{
    __shared__ __align__(16) unsigned short As[16 * 512];   // 16 KB
    __shared__ __align__(16) unsigned short Ws[4 * 512];    // 4 KB
    __shared__ float ps[4];

    int tid = threadIdx.x, l = tid & 63, w = tid >> 6;
    int bn = blockIdx.x * 32, bm = blockIdx.y * 128;
    int rsel = l & 15, ksel = (l >> 4) * 8;

    const unsigned short* ap[4];
#pragma unroll
    for (int i = 0; i < 4; ++i) {
        int s = 4 * w + i, mt = s >> 1, subk = s & 1;
        ap[i] = A + (size_t)(bm + mt * 16 + rsel) * lda + subk * 32 + ksel;
    }
    int nt = w >> 1, wsub = w & 1;
    int nr = bn + nt * 16 + rsel; if (nr >= N) nr = N - 1;
    const unsigned short* wp = W + (size_t)nr * K + wsub * 32 + ksel;

    f32x4 acc[2][2] = {};

    for (int k0 = 0; k0 < K; k0 += 64) {
        __syncthreads();
#pragma unroll
        for (int i = 0; i < 4; ++i)
            __builtin_amdgcn_global_load_lds(
                (const __attribute__((address_space(1))) unsigned int*)(ap[i]),
                (__attribute__((address_space(3))) unsigned int*)(As + (4 * w + i) * 512),
                16, 0, 0);
        __builtin_amdgcn_global_load_lds(
            (const __attribute__((address_space(1))) unsigned int*)(wp),
            (__attribute__((address_space(3))) unsigned int*)(Ws + w * 512),
            16, 0, 0);
        ap[0] += 64; ap[1] += 64; ap[2] += 64; ap[3] += 64; wp += 64;
        __syncthreads();
#pragma unroll
        for (int subk = 0; subk < 2; ++subk) {
            bf16x8 a0 = *(const bf16x8*)(As + (4 * w + subk) * 512 + l * 8);
            bf16x8 a1 = *(const bf16x8*)(As + (4 * w + 2 + subk) * 512 + l * 8);
            bf16x8 b0 = *(const bf16x8*)(Ws + subk * 512 + l * 8);
            bf16x8 b1 = *(const bf16x8*)(Ws + (2 + subk) * 512 + l * 8);
            acc[0][0] = __builtin_amdgcn_mfma_f32_16x16x32_bf16(a0, b0, acc[0][0], 0, 0, 0);
            acc[0][1] = __builtin_amdgcn_mfma_f32_16x16x32_bf16(a0, b1, acc[0][1], 0, 0, 0);
            acc[1][0] = __builtin_amdgcn_mfma_f32_16x16x32_bf16(a1, b0, acc[1][0], 0, 0, 0);
            acc[1][1] = __builtin_amdgcn_mfma_f32_16x16x32_bf16(a1, b1, acc[1][1], 0, 0, 0);
        }
    }

    int rg4 = (l >> 4) * 4, cc = l & 15;
    if (mode == 1) {
        int act = actp[blockIdx.y];
        float s = 0.f;
#pragma unroll
        for (int mi = 0; mi < 2; ++mi) {
            int mt = 2 * w + mi;
#pragma unroll
            for (int ni = 0; ni < 2; ++ni) {
                int col = bn + ni * 16 + cc;
                float bb = bias[col];
#pragma unroll
                for (int rg = 0; rg < 4; ++rg) {
                    int row = bm + mt * 16 + rg4 + rg;
                    float v = acc[mi][ni][rg] + bb - sub[(size_t)row * 1024 + col];
                    if ((row & 127) < act) s += v * v;
                }
            }
        }
        for (int o = 32; o > 0; o >>= 1) s += __shfl_down(s, o, 64);
        if (l == 0) ps[w] = s;
        __syncthreads();
        if (tid == 0) {
            float tot = ps[0] + ps[1] + ps[2] + ps[3];
            atomicAdd(lossp, tot * (0.005f / (float)act));
        }
        return;
    }

    if (mode == 3) {
#pragma unroll
        for (int mi = 0; mi < 2; ++mi) {
            int mt = 2 * w + mi;
#pragma unroll
            for (int ni = 0; ni < 2; ++ni) {
                int col = bn + ni * 16 + cc;
                if (col >= N) continue;
                float bb = bias[col];
#pragma unroll
                for (int rg = 0; rg < 4; ++rg) {
                    int row = bm + mt * 16 + rg4 + rg;
                    int tt = row >> 7, b = row & 127;
                    float v = acc[mi][ni][rg] + bb;
                    if (b >= actp[tt]) v = 0.f;
                    C[(size_t)b * ((size_t)TD * V) + (size_t)tt * V + col] = v;
                }
            }
        }
        return;
    }

    int act = (mode == 2) ? *actp : (1 << 30);
#pragma unroll
    for (int mi = 0; mi < 2; ++mi) {
        int mt = 2 * w + mi;
#pragma unroll
        for (int ni = 0; ni < 2; ++ni) {
            int col = bn + ni * 16 + cc;
            if (col >= N) continue;
            float bb = bias[col];
            if (bias2) bb += bias2[col];
#pragma unroll
            for (int rg = 0; rg < 4; ++rg) {
                int row = bm + mt * 16 + rg4 + rg;
                float v = acc[mi][ni][rg] + bb;
                if (mode == 2 && row >= act) v = 0.f;
                C[(size_t)row * ldc + col] = v;
            }
        }
    }
}

// LSTM pointwise: h,c update; optional prevh capture; bf16 h into up to 3 slots;
// optional emb-slot prefetch for the NEXT timestep (folded k_embslot).
__global__ void k_lstm(const float* __restrict__ gates, int ldg,
                       float* __restrict__ h, float* __restrict__ c,
                       const int* __restrict__ actp, float* __restrict__ prevh,
                       unsigned short* __restrict__ s1, int ld1,
                       unsigned short* __restrict__ s2, int ld2,
                       unsigned short* __restrict__ s3, int ld3,
                       const unsigned short* __restrict__ embs_bf,
                       unsigned short* __restrict__ xtd_emb, int tnext)
{
    int idx = blockIdx.x * 256 + threadIdx.x;   // 131072
    if (embs_bf && idx < B * 128) {             // all rows, before act check
        int be = idx >> 7, e8 = (idx & 127) << 3;
        *(uint4*)(xtd_emb + (size_t)be * 5120 + 3072 + e8) =
            *(const uint4*)(embs_bf + (((size_t)(be * TD + tnext)) << 10) + e8);
    }
    int b = idx >> 10;
    if (b >= *actp) return;                     // frozen rows keep state + slots
    int n = idx & 1023;
    const float* g = gates + (size_t)b * ldg;
    float gi = g[n], gf = g[1024 + n], gg = g[2048 + n], go = g[3072 + n];
    if (prevh) prevh[idx] = h[idx];
    float cc = c[idx];
    float c2 = sigm(gf) * cc + sigm(gi) * tanhf(gg);
    c[idx] = c2;
    float hv = sigm(go) * tanhf(c2);
    h[idx] = hv;
    unsigned short hb = f2bf(hv);
    if (s1) s1[(size_t)b * ld1 + n] = hb;
    if (s2) s2[(size_t)b * ld2 + n] = hb;
    if (s3) s3[(size_t)b * ld3 + n] = hb;
}

// attention: e = relu(h1a + img_att).aw_w + aw_b ; softmax over 36 ;
// awe = alpha^T feats_bf -> bf16 into xlg slot [0,2048)
__global__ __launch_bounds__(256)
void k_attn(const float* __restrict__ h1a, int ldh, const float* __restrict__ img_att,
            const float* __restrict__ aw_w, const float* __restrict__ aw_b,
            const unsigned short* __restrict__ feats_bf,
            unsigned short* __restrict__ xlg)
{
    int b = blockIdx.x;
    int tid = threadIdx.x;
    __shared__ float sh[A_DIM];
    __shared__ float se[NR];
    for (int i = tid; i < A_DIM; i += 256) sh[i] = h1a[(size_t)b * ldh + i];
    __syncthreads();
    int wid = tid >> 6, lane = tid & 63;
    for (int r = wid; r < NR; r += 4) {
        const float* row = img_att + ((size_t)b * NR + r) * A_DIM;
        float s = 0.f;
        for (int a = lane; a < A_DIM; a += 64)
            s += fmaxf(sh[a] + row[a], 0.f) * aw_w[a];
        for (int off = 32; off > 0; off >>= 1) s += __shfl_down(s, off, 64);
        if (lane == 0) se[r] = s + aw_b[0];
    }
    __syncthreads();
    if (tid == 0) {
        float m = se[0];
        for (int r = 1; r < NR; ++r) m = fmaxf(m, se[r]);
        float ssum = 0.f;
        for (int r = 0; r < NR; ++r) { float ex = __expf(se[r] - m); se[r] = ex; ssum += ex; }
        float inv = 1.f / ssum;
        for (int r = 0; r < NR; ++r) se[r] *= inv;
    }
    __syncthreads();
    const unsigned short* fb = feats_bf + (size_t)b * NR * F;
    for (int f = tid; f < F; f += 256) {
        float s = 0.f;
        for (int r = 0; r < NR; ++r) s += se[r] * bf2f(fb[(size_t)r * F + f]);
        xlg[(size_t)b * 4096 + f] = f2bf(s);
    }
}

// ---------------------------------------------------------------------------
extern "C" void kernel_launch(void* const* d_in, const int* in_sizes, int n_in,
                              void* d_out, int out_size, void* d_ws, size_t ws_size,
                              hipStream_t stream)
{
    const float* feats     = (const float*)d_in[0];
    const int*   sequences = (const int*)d_in[1];
    const int*   sizes     = (const int*)d_in[2];
    const float* emb       = (const float*)d_in[3];
    const float* td_wi = (const float*)d_in[4];
    const float* td_wh = (const float*)d_in[5];
    const float* td_bi = (const float*)d_in[6];
    const float* td_bh = (const float*)d_in[7];
    const float* lg_wi = (const float*)d_in[8];
    const float* lg_wh = (const float*)d_in[9];
    const float* lg_bi = (const float*)d_in[10];
    const float* lg_bh = (const float*)d_in[11];
    const float* ar_wi = (const float*)d_in[12];
    const float* ar_wh = (const float*)d_in[13];
    const float* ar_bi = (const float*)d_in[14];
    const float* ar_bh = (const float*)d_in[15];
    const float* arl_w = (const float*)d_in[16];
    const float* arl_b = (const float*)d_in[17];
    const float* out_w = (const float*)d_in[18];
    const float* out_b = (const float*)d_in[19];
    const float* af_w  = (const float*)d_in[20];
    const float* af_b  = (const float*)d_in[21];
    const float* ad_w  = (const float*)d_in[22];
    const float* ad_b  = (const float*)d_in[23];
    const float* aw_w  = (const float*)d_in[24];
    const float* aw_b  = (const float*)d_in[25];
    float* out = (float*)d_out;

    // ---- workspace carve (floats; every region multiple of 4 floats) ----
    float* ws = (float*)d_ws;
    size_t off = 0;
    auto alloc = [&](size_t n) { float* p = ws + off; off += n; return p; };
    // zero region: 6 f32 states + xtd + xlg + xar (contiguous)
    float* h1   = alloc((size_t)BD);
    float* c1   = alloc((size_t)BD);
    float* h2   = alloc((size_t)BD);
    float* c2   = alloc((size_t)BD);
    float* arh  = alloc((size_t)BD);
    float* arc  = alloc((size_t)BD);
    unsigned short* xtd = (unsigned short*)alloc((size_t)B * 5120 / 2);
    unsigned short* xlg = (unsigned short*)alloc((size_t)B * 4096 / 2);
    unsigned short* xar = (unsigned short*)alloc((size_t)B * 2048 / 2);
    int zero_n = 6 * BD + (B * 5120 + B * 4096 + B * 2048) / 2;  // 1,507,328
    // rest
    float* gates     = alloc((size_t)B * 4096);
    float* gates2    = alloc((size_t)B * 5120);          // [ar gates | h1a]
    float* prevh_all = alloc((size_t)(TD - 1) * BD);     // f32 h1 history (t=1..18)
    float* img_att   = alloc((size_t)B * NR * A_DIM);
    float* bias_comb = alloc(5120);
    unsigned short* embs_bf  = (unsigned short*)alloc((size_t)B * TD * E / 2);
    unsigned short* feats_bf = (unsigned short*)alloc((size_t)B * NR * F / 2);
    unsigned short* Hout     = (unsigned short*)alloc((size_t)TD * BD / 2);       // h2 history
    unsigned short* Arout    = (unsigned short*)alloc((size_t)(TD - 1) * BD / 2); // arh history
    unsigned short* Wtd  = (unsigned short*)alloc((size_t)4096 * 5120 / 2);
    unsigned short* Wlg  = (unsigned short*)alloc((size_t)4096 * 4096 / 2);
    unsigned short* Wcomb = (unsigned short*)alloc((size_t)5120 * 2048 / 2);  // [War | Wad-pad]
    unsigned short* Wout = (unsigned short*)alloc((size_t)V * 1024 / 2);
    unsigned short* Warl = (unsigned short*)alloc((size_t)1024 * 1024 / 2);
    unsigned short* Waf  = (unsigned short*)alloc((size_t)1024 * 2048 / 2);
    int* ip     = (int*)(ws + off);
    int* order  = ip; ip += B;
    int* active = ip; ip += TD + 1;
    int* seqs_s = ip; ip += B * T;

    float* loss_ptr = out + (size_t)B * TD * V + B * T + B;

    // ---- prologue ----
    k_sort_init<<<1, B, 0, stream>>>(sizes, sequences, order, active, seqs_s, out);
    k_zero<<<(zero_n + 255) / 256, 256, 0, stream>>>(h1, zero_n);
    k_favg<<<1024, 256, 0, stream>>>(feats, order, xtd);
    k_emb2bf<<<(B * TD * 128 + 255) / 256, 256, 0, stream>>>(emb, seqs_s, embs_bf);
    k_feats2bf<<<4608, 256, 0, stream>>>(feats, order, feats_bf);
    k_w2bf<<<10240, 256, 0, stream>>>(td_wi, 4096, td_wh, 1024, Wtd, (long)4096 * 640);
    k_w2bf<<<8192, 256, 0, stream>>>(lg_wi, 3072, lg_wh, 1024, Wlg, (long)4096 * 512);
    k_w2bf<<<4096, 256, 0, stream>>>(ar_wi, 1024, ar_wh, 1024, Wcomb, (long)4096 * 256);
    k_w2bf<<<1024, 256, 0, stream>>>(ad_w, 1024, nullptr, 1024,
                                     Wcomb + (size_t)4096 * 2048, (long)1024 * 256);
    k_w2bf<<<5000, 256, 0, stream>>>(out_w, 1024, nullptr, 0, Wout, (long)V * 128);
    k_w2bf<<<512, 256, 0, stream>>>(arl_w, 1024, nullptr, 0, Warl, (long)1024 * 128);
    k_w2bf<<<1024, 256, 0, stream>>>(af_w, 2048, nullptr, 0, Waf, (long)1024 * 256);
    k_biascomb<<<20, 256, 0, stream>>>(ar_bi, ar_bh, ad_b, bias_comb);
    // img_att = feats_bf @ Waf^T + af_b   [4608 x 1024]
    k_gemm<<<dim3(32, 36), 256, 0, stream>>>(
        feats_bf, 2048, Waf, 2048, af_b, nullptr,
        img_att, 1024, 1024, 0, nullptr, nullptr, nullptr);
    k_embslot<<<64, 256, 0, stream>>>(embs_bf, xtd, 0);   // emb slot for t=0

    // ---- timestep loop (7 dispatches each) ----
    for (int t = 0; t < TD; ++t) {
        const int* actp = active + t;
        // top-down LSTM gates
        k_gemm<<<dim3(128, 1), 256, 0, stream>>>(
            xtd, 5120, Wtd, 5120, td_bi, td_bh,
            gates, 4096, 4096, 0, nullptr, nullptr, nullptr);
        k_lstm<<<512, 256, 0, stream>>>(gates, 4096, h1, c1, actp,
            (t > 0) ? prevh_all + (size_t)(t - 1) * BD : nullptr,
            xtd + 4096, 5120, xlg + 2048, 4096, xar, 2048,
            nullptr, nullptr, 0);
        // combined ARNet-gates + attention-projection GEMM:
        //   A = xar [h1 | arh], W = [War | Wad-pad] -> gates2 [128 x 5120]
        k_gemm<<<dim3(160, 1), 256, 0, stream>>>(
            xar, 2048, Wcomb, 2048, bias_comb, nullptr,
            gates2, 5120, 5120, 0, nullptr, nullptr, nullptr);
        k_attn<<<B, 256, 0, stream>>>(gates2 + 4096, 5120, img_att, aw_w, aw_b,
                                      feats_bf, xlg);
        // language LSTM gates
        k_gemm<<<dim3(128, 1), 256, 0, stream>>>(
            xlg, 4096, Wlg, 4096, lg_bi, lg_bh,
            gates, 4096, 4096, 0, nullptr, nullptr, nullptr);
        // h2 update + h2 history store + emb-slot prefetch for t+1
        k_lstm<<<512, 256, 0, stream>>>(gates, 4096, h2, c2, actp, nullptr,
            xtd, 5120, xlg + 3072, 4096, Hout + (size_t)t * BD, 1024,
            (t + 1 < TD) ? embs_bf : (const unsigned short*)nullptr, xtd, t + 1);
        // ARNet LSTM update + arh history store
        k_lstm<<<512, 256, 0, stream>>>(gates2, 5120, arh, arc, actp, nullptr,
            xar + 1024, 2048,
            (t > 0) ? Arout + (size_t)(t - 1) * BD : (unsigned short*)nullptr, 1024,
            nullptr, 0, nullptr, nullptr, 0);
    }

    // ---- deferred batched GEMMs ----
    // ARNet loss over t=1..18: (Arout @ Warl^T + arl_b - prevh_all)^2 masked
    k_gemm<<<dim3(32, TD - 1), 256, 0, stream>>>(
        Arout, 1024, Warl, 1024, arl_b, nullptr,
        nullptr, 0, 1024, 1, prevh_all, active + 1, loss_ptr);
    // preds for all timesteps: [19*128 x 1024] @ Wout^T -> out[b][t][v]
    k_gemm<<<dim3((V + 31) / 32, TD), 256, 0, stream>>>(
        Hout, 1024, Wout, 1024, out_b, nullptr,
        out, 0, V, 3, nullptr, active, nullptr);
}

// Round 2
// 4106.023 us; speedup vs baseline: 1.5660x; 1.3575x over previous
//
#include <hip/hip_runtime.h>
#include <math.h>

#define B    128
#define T    20
#define TD   19      // Tdec
#define V    10000
#define D    1024
#define E    1024
#define A_DIM 1024
#define F    2048
#define NR   36
#define BD   (B * D)  // 131072

typedef __attribute__((ext_vector_type(8))) short bf16x8;
typedef __attribute__((ext_vector_type(4))) float f32x4;

__device__ __forceinline__ float sigm(float x) { return 1.f / (1.f + __expf(-x)); }

__device__ __forceinline__ unsigned short f2bf(float f) {
    union { float f; unsigned u; } x; x.f = f;
    unsigned r = x.u + 0x7fffu + ((x.u >> 16) & 1u);
    return (unsigned short)(r >> 16);
}
__device__ __forceinline__ float bf2f(unsigned short u) {
    union { float f; unsigned u; } x; x.u = ((unsigned)u) << 16; return x.f;
}
__device__ __forceinline__ uint4 pack8(const float* __restrict__ src) {
    float4 a = *(const float4*)src, b = *(const float4*)(src + 4);
    union { unsigned short u[8]; uint4 v; } p;
    p.u[0] = f2bf(a.x); p.u[1] = f2bf(a.y); p.u[2] = f2bf(a.z); p.u[3] = f2bf(a.w);
    p.u[4] = f2bf(b.x); p.u[5] = f2bf(b.y); p.u[6] = f2bf(b.z); p.u[7] = f2bf(b.w);
    return p.v;
}

// ---------------------------------------------------------------------------
// Sort (stable descending by sizes), seqs/order outputs, active counts
// ---------------------------------------------------------------------------
__global__ void k_sort_init(const int* __restrict__ sizes,
                            const int* __restrict__ sequences,
                            int* __restrict__ order,
                            int* __restrict__ active,
                            int* __restrict__ seqs_s,
                            float* __restrict__ out)
{
    int tid = threadIdx.x;                // 128 threads
    __shared__ int s_sizes[B];
    __shared__ int s_dl[B];
    s_sizes[tid] = sizes[tid];
    __syncthreads();
    int si = s_sizes[tid];
    int rank = 0;
    for (int j = 0; j < B; ++j) {
        int sj = s_sizes[j];
        if (sj > si || (sj == si && j < tid)) rank++;
    }
    order[rank] = tid;
    __syncthreads();
    int ob = order[tid];
    int dl = s_sizes[ob] - 1;
    s_dl[tid] = dl;
    for (int tt = 0; tt < T; ++tt) {
        int sq = sequences[ob * T + tt];
        seqs_s[tid * T + tt] = sq;
        out[(size_t)B * TD * V + tid * T + tt] = (float)sq;
    }
    out[(size_t)B * TD * V + B * T + tid] = (float)ob;
    __syncthreads();
    if (tid < TD) {
        int c = 0;
        for (int b = 0; b < B; ++b) c += (s_dl[b] > tid) ? 1 : 0;
        active[tid] = c;
    }
    if (tid == 0) out[(size_t)B * TD * V + B * T + B] = 0.f;   // loss accumulator
}

__global__ void k_zero(float* __restrict__ p, int n) {
    int i = blockIdx.x * 256 + threadIdx.x;
    if (i < n) p[i] = 0.f;
}

// weight f32 -> bf16, rows concatenated [s1 row (K1) | s2 row (K2)]
// s2 == nullptr with K2 > 0: zero-pad the K2 region.
// il == 1: gate-interleave row permutation: src row = (r&3)*1024 + (r>>2)
__global__ void k_w2bf(const float* __restrict__ s1, int K1,
                       const float* __restrict__ s2, int K2,
                       unsigned short* __restrict__ dst, long total /*granules*/,
                       int il)
{
    long g = (long)blockIdx.x * 256 + threadIdx.x;
    if (g >= total) return;
    int Kt = K1 + K2;
    int gpr = Kt >> 3;
    int row = (int)(g / gpr);
    int k8 = (int)(g % gpr) << 3;
    if (k8 >= K1 && !s2) {
        uint4 z{};
        *(uint4*)(dst + ((size_t)g << 3)) = z;
        return;
    }
    int srow = il ? ((row & 3) * 1024 + (row >> 2)) : row;
    const float* src = (k8 < K1) ? (s1 + (size_t)srow * K1 + k8)
                                 : (s2 + (size_t)srow * K2 + (k8 - K1));
    *(uint4*)(dst + ((size_t)g << 3)) = pack8(src);
}

// feats (sorted by order) -> bf16 [4608 x 2048]
__global__ void k_feats2bf(const float* __restrict__ feats, const int* __restrict__ order,
                           unsigned short* __restrict__ dst)
{
    long g = (long)blockIdx.x * 256 + threadIdx.x;   // 4608*256 granules
    int row = (int)(g >> 8);
    int k8 = ((int)g & 255) << 3;
    int b = row / NR, r = row - b * NR;
    const float* src = feats + ((size_t)order[b] * NR + r) * F + k8;
    *(uint4*)(dst + (size_t)row * F + k8) = pack8(src);
}

// featsAvg -> bf16 directly into xtd slot [1024,3072)
__global__ void k_favg(const float* __restrict__ feats, const int* __restrict__ order,
                       unsigned short* __restrict__ xtd)
{
    int idx = blockIdx.x * 256 + threadIdx.x;   // B*F = 262144
    int b = idx >> 11, f = idx & 2047;
    const float* base = feats + (size_t)order[b] * NR * F + f;
    float s = 0.f;
#pragma unroll
    for (int r = 0; r < NR; ++r) s += base[(size_t)r * F];
    xtd[(size_t)b * 5120 + 1024 + f] = f2bf(s * (1.f / NR));
}

// embeddings (sorted) -> bf16 [B x TD x 1024]
__global__ void k_emb2bf(const float* __restrict__ emb, const int* __restrict__ seqs_s,
                         unsigned short* __restrict__ embs_bf)
{
    long g = (long)blockIdx.x * 256 + threadIdx.x;  // B*TD*128 granules
    if (g >= (long)B * TD * 128) return;
    int b = (int)(g / (TD * 128));
    int rem = (int)(g - (long)b * (TD * 128));
    int t = rem >> 7, e8 = (rem & 127) << 3;
    const float* src = emb + (size_t)seqs_s[b * T + t] * E + e8;
    *(uint4*)(embs_bf + (((size_t)(b * TD + t)) << 10) + e8) = pack8(src);
}

// copy embs_bf[:,t,:] into xtd emb slot [3072,4096)  (used once, t=0)
__global__ void k_embslot(const unsigned short* __restrict__ embs_bf,
                          unsigned short* __restrict__ xtd, int t)
{
    int g = blockIdx.x * 256 + threadIdx.x;  // B*128 = 16384
    int b = g >> 7, e8 = (g & 127) << 3;
    *(uint4*)(xtd + (size_t)b * 5120 + 3072 + e8) =
        *(const uint4*)(embs_bf + (((size_t)(b * TD + t)) << 10) + e8);
}

// interleaved combined bias: dst[j*4+g] = bi[g*1024+j] + bh[g*1024+j]
// i >= 4096 (if n > 4096): dst[i] = extra[i-4096]
__global__ void k_biasint(const float* __restrict__ bi, const float* __restrict__ bh,
                          const float* __restrict__ extra, float* __restrict__ dst, int n)
{
    int i = blockIdx.x * 256 + threadIdx.x;
    if (i >= n) return;
    if (i < 4096) {
        int j = i >> 2, g = i & 3;
        dst[i] = bi[g * 1024 + j] + bh[g * 1024 + j];
    } else {
        dst[i] = extra[i - 4096];
    }
}

// ---------------------------------------------------------------------------
// Shared GEMM core: C[m][n] = sum_k A[m][k]*W[n][k], tile M=128 x N=32, BK=64,
// 256 threads (4 waves). 4-deep LDS prefetch pipeline (T3+T4):
//   prologue stages 4 tiles; main loop: vmcnt(15) -> barrier -> compute ->
//   barrier -> restage; tail drains with vmcnt(0).
// smem layout: 4 buffers x (A 8192 ushort | W 2048 ushort) = 81920 B.
// NOTE: no other VMEM ops may be issued before/inside this loop (vmcnt count).
// ---------------------------------------------------------------------------
__device__ __forceinline__ void gemm_core(
    const unsigned short* __restrict__ A, int lda,
    const unsigned short* __restrict__ W, int K, int N,
    unsigned short* __restrict__ smem,
    int bm, int bn, f32x4 (&acc)[2][2])
{
    int tid = threadIdx.x, l = tid & 63, w = tid >> 6;
    int rsel = l & 15, ksel = (l >> 4) * 8;

    const unsigned short* ap[4];
#pragma unroll
    for (int i = 0; i < 4; ++i) {
        int s = 4 * w + i, mt = s >> 1, subk = s & 1;
        ap[i] = A + (size_t)(bm + mt * 16 + rsel) * lda + subk * 32 + ksel;
    }
    int nt_w = w >> 1, wsub = w & 1;
    int nr = bn + nt_w * 16 + rsel; if (nr >= N) nr = N - 1;
    const unsigned short* wp = W + (size_t)nr * K + wsub * 32 + ksel;
    int ntile = K >> 6;

    auto stage = [&](int p) {
        unsigned short* As = smem + p * 10240;
        unsigned short* Ws = As + 8192;
#pragma unroll
        for (int i = 0; i < 4; ++i)
            __builtin_amdgcn_global_load_lds(
                (const __attribute__((address_space(1))) unsigned int*)(ap[i]),
                (__attribute__((address_space(3))) unsigned int*)(As + (4 * w + i) * 512),
                16, 0, 0);
        __builtin_amdgcn_global_load_lds(
            (const __attribute__((address_space(1))) unsigned int*)(wp),
            (__attribute__((address_space(3))) unsigned int*)(Ws + w * 512),
            16, 0, 0);
        ap[0] += 64; ap[1] += 64; ap[2] += 64; ap[3] += 64; wp += 64;
    };
    auto compute = [&](int p) {
        unsigned short* As = smem + p * 10240;
        unsigned short* Ws = As + 8192;
#pragma unroll
        for (int subk = 0; subk < 2; ++subk) {
            bf16x8 a0 = *(const bf16x8*)(As + (4 * w + subk) * 512 + l * 8);
            bf16x8 a1 = *(const bf16x8*)(As + (4 * w + 2 + subk) * 512 + l * 8);
            bf16x8 b0 = *(const bf16x8*)(Ws + subk * 512 + l * 8);
            bf16x8 b1 = *(const bf16x8*)(Ws + (2 + subk) * 512 + l * 8);
            acc[0][0] = __builtin_amdgcn_mfma_f32_16x16x32_bf16(a0, b0, acc[0][0], 0, 0, 0);
            acc[0][1] = __builtin_amdgcn_mfma_f32_16x16x32_bf16(a0, b1, acc[0][1], 0, 0, 0);
            acc[1][0] = __builtin_amdgcn_mfma_f32_16x16x32_bf16(a1, b0, acc[1][0], 0, 0, 0);
            acc[1][1] = __builtin_amdgcn_mfma_f32_16x16x32_bf16(a1, b1, acc[1][1], 0, 0, 0);
        }
    };

    // prologue: stage tiles 0..3 (K >= 1024 everywhere -> ntile >= 16 > 4)
    stage(0); stage(1); stage(2); stage(3);
    int t = 0;
    for (; t + 4 < ntile; ++t) {
        asm volatile("s_waitcnt vmcnt(15)" ::: "memory");   // tile t landed (3 in flight)
        __builtin_amdgcn_s_barrier();
        compute(t & 3);
        __builtin_amdgcn_s_barrier();                        // all waves done reading buf
        stage(t & 3);                                        // stage tile t+4
    }
    for (; t < ntile; ++t) {                                 // tail: no more staging
        asm volatile("s_waitcnt vmcnt(0)" ::: "memory");
        __builtin_amdgcn_s_barrier();
        compute(t & 3);
        __builtin_amdgcn_s_barrier();
    }
}

// ---------------------------------------------------------------------------
// Plain MFMA GEMM (modes 0 / 1 / 3)
//   0: store C = acc + bias
//   1: batched ARNet loss (no store): per blockIdx.y (= t-1), act=actp[y];
//      sum (acc+bias-sub)^2 over (row&127)<act -> atomicAdd(lossp,*0.005/act)
//   3: batched pred store, grid (TD, nPanels) with axes swapped in-kernel:
//      row=t*128+b -> out[b][t][col], zero if b>=actp[t]
// ---------------------------------------------------------------------------
__global__ __launch_bounds__(256)
void k_gemm(const unsigned short* __restrict__ A, int lda,
            const unsigned short* __restrict__ W, int K,
            const float* __restrict__ bias,
            float* __restrict__ C, int ldc, int N,
            int mode, const float* __restrict__ sub, const int* __restrict__ actp,
            float* __restrict__ lossp)
{
    __shared__ __align__(16) unsigned short smem[4 * 10240];   // 80 KB
    __shared__ float ps[4];

    int bxp = blockIdx.x, byp = blockIdx.y;
    if (mode == 3) { int tswap = bxp; bxp = byp; byp = tswap; }
    int bn = bxp * 32, bm = byp * 128;
    int tid = threadIdx.x, l = tid & 63, w = tid >> 6;

    f32x4 acc[2][2] = {};
    gemm_core(A, lda, W, K, N, smem, bm, bn, acc);

    int rg4 = (l >> 4) * 4, cc = l & 15;
    if (mode == 1) {
        int act = actp[byp];
        float s = 0.f;
#pragma unroll
        for (int mi = 0; mi < 2; ++mi) {
            int mt = 2 * w + mi;
#pragma unroll
            for (int ni = 0; ni < 2; ++ni) {
                int col = bn + ni * 16 + cc;
                float bb = bias[col];
#pragma unroll
                for (int rg = 0; rg < 4; ++rg) {
                    int row = bm + mt * 16 + rg4 + rg;
                    float v = acc[mi][ni][rg] + bb - sub[(size_t)row * 1024 + col];
                    if ((row & 127) < act) s += v * v;
                }
            }
        }
        for (int o = 32; o > 0; o >>= 1) s += __shfl_down(s, o, 64);
        if (l == 0) ps[w] = s;
        __syncthreads();
        if (tid == 0) {
            float tot = ps[0] + ps[1] + ps[2] + ps[3];
            atomicAdd(lossp, tot * (0.005f / (float)act));
        }
        return;
    }

    if (mode == 3) {
#pragma unroll
        for (int mi = 0; mi < 2; ++mi) {
            int mt = 2 * w + mi;
#pragma unroll
            for (int ni = 0; ni < 2; ++ni) {
                int col = bn + ni * 16 + cc;
                if (col >= N) continue;
                float bb = bias[col];
#pragma unroll
                for (int rg = 0; rg < 4; ++rg) {
                    int row = bm + mt * 16 + rg4 + rg;
                    int tt = row >> 7, b = row & 127;
                    float v = acc[mi][ni][rg] + bb;
                    if (b >= actp[tt]) v = 0.f;
                    C[(size_t)b * ((size_t)TD * V) + (size_t)tt * V + col] = v;
                }
            }
        }
        return;
    }

#pragma unroll
    for (int mi = 0; mi < 2; ++mi) {
        int mt = 2 * w + mi;
#pragma unroll
        for (int ni = 0; ni < 2; ++ni) {
            int col = bn + ni * 16 + cc;
            if (col >= N) continue;
            float bb = bias[col];
#pragma unroll
            for (int rg = 0; rg < 4; ++rg) {
                int row = bm + mt * 16 + rg4 + rg;
                C[(size_t)row * ldc + col] = acc[mi][ni][rg] + bb;
            }
        }
    }
}

// ---------------------------------------------------------------------------
// Fused gate-GEMM + LSTM pointwise. W rows are gate-interleaved (r'=j*4+g) so
// block bn<NL owns all 4 gates of units [bn/4, bn/4+8). Epilogue exchanges
// gates via LDS and applies the LSTM update + bf16 slot stores in-block.
// Blocks with bn>=NL store acc+bias to C2 (h1a path of the comb GEMM).
// Optional emb-slot prefetch for the next timestep (lg GEMM only).
// ---------------------------------------------------------------------------
__global__ __launch_bounds__(256)
void k_gemm_lstm(const unsigned short* __restrict__ A, int lda,
                 const unsigned short* __restrict__ W, int K,
                 const float* __restrict__ biasI, int NL, int N,
                 float* __restrict__ h, float* __restrict__ c,
                 const int* __restrict__ actp,
                 float* __restrict__ prevh,
                 unsigned short* __restrict__ s1, int ld1,
                 unsigned short* __restrict__ s2, int ld2,
                 unsigned short* __restrict__ s3, int ld3,
                 float* __restrict__ C2,
                 const unsigned short* __restrict__ embs_bf,
                 unsigned short* __restrict__ xtd_emb, int tnext)
{
    __shared__ __align__(16) unsigned short smem[4 * 10240];   // 80 KB

    int tid = threadIdx.x, l = tid & 63, w = tid >> 6;
    int bn = blockIdx.x * 32;

    f32x4 acc[2][2] = {};
    gemm_core(A, lda, W, K, N, smem, 0, bn, acc);

    int rg4 = (l >> 4) * 4, cc = l & 15;

    if (bn >= NL) {
        // plain f32 store (h1a): C2 is [128 x (N-NL)]
        int ldc2 = N - NL;
#pragma unroll
        for (int mi = 0; mi < 2; ++mi) {
            int mt = 2 * w + mi;
#pragma unroll
            for (int ni = 0; ni < 2; ++ni) {
                int col = bn + ni * 16 + cc;
                float bb = biasI[col];
#pragma unroll
                for (int rg = 0; rg < 4; ++rg) {
                    int row = mt * 16 + rg4 + rg;
                    C2[(size_t)row * ldc2 + (col - NL)] = acc[mi][ni][rg] + bb;
                }
            }
        }
        return;
    }

    // stash gates (acc + bias) into LDS: Ls[row][col_local]
    float* Ls = (float*)smem;   // 128*32 f32 = 16 KB, buffers drained
#pragma unroll
    for (int mi = 0; mi < 2; ++mi) {
        int mt = 2 * w + mi;
#pragma unroll
        for (int ni = 0; ni < 2; ++ni) {
            int col = bn + ni * 16 + cc;
            float bb = biasI[col];
#pragma unroll
            for (int rg = 0; rg < 4; ++rg) {
                int row = mt * 16 + rg4 + rg;
                Ls[row * 32 + (col - bn)] = acc[mi][ni][rg] + bb;
            }
        }
    }
    __syncthreads();

    int act = *actp;
    int j0 = bn >> 2;
    for (int e = tid; e < 128 * 8; e += 256) {
        int row = e >> 3, jl = e & 7;
        if (row < act) {
            const float* g = Ls + row * 32 + jl * 4;     // i,f,g,o
            int j = j0 + jl;
            size_t ix = (size_t)row * 1024 + j;
            if (prevh) prevh[ix] = h[ix];
            float c2v = sigm(g[1]) * c[ix] + sigm(g[0]) * tanhf(g[2]);
            c[ix] = c2v;
            float hv = sigm(g[3]) * tanhf(c2v);
            h[ix] = hv;
            unsigned short hb = f2bf(hv);
            if (s1) s1[(size_t)row * ld1 + j] = hb;
            if (s2) s2[(size_t)row * ld2 + j] = hb;
            if (s3) s3[(size_t)row * ld3 + j] = hb;
        }
    }

    // folded emb-slot prefetch for next timestep (lg GEMM, all 128 blocks)
    if (embs_bf && tid < 128) {
        int gI = blockIdx.x * 128 + tid;     // 128*128 = 16384 granules
        int be = gI >> 7, e8 = (gI & 127) << 3;
        *(uint4*)(xtd_emb + (size_t)be * 5120 + 3072 + e8) =
            *(const uint4*)(embs_bf + (((size_t)(be * TD + tnext)) << 10) + e8);
    }
}

// attention: e = relu(h1a + img_att).aw_w + aw_b ; softmax over 36 ;
// awe = alpha^T feats_bf -> bf16 into xlg slot [0,2048)
__global__ __launch_bounds__(256)
void k_attn(const float* __restrict__ h1a, int ldh, const float* __restrict__ img_att,
            const float* __restrict__ aw_w, const float* __restrict__ aw_b,
            const unsigned short* __restrict__ feats_bf,
            unsigned short* __restrict__ xlg)
{
    int b = blockIdx.x;
    int tid = threadIdx.x;
    __shared__ float sh[A_DIM];
    __shared__ float se[NR];
    for (int i = tid; i < A_DIM; i += 256) sh[i] = h1a[(size_t)b * ldh + i];
    __syncthreads();
    int wid = tid >> 6, lane = tid & 63;
    for (int r = wid; r < NR; r += 4) {
        const float* row = img_att + ((size_t)b * NR + r) * A_DIM;
        float s = 0.f;
        for (int a = lane; a < A_DIM; a += 64)
            s += fmaxf(sh[a] + row[a], 0.f) * aw_w[a];
        for (int off = 32; off > 0; off >>= 1) s += __shfl_down(s, off, 64);
        if (lane == 0) se[r] = s + aw_b[0];
    }
    __syncthreads();
    if (tid == 0) {
        float m = se[0];
        for (int r = 1; r < NR; ++r) m = fmaxf(m, se[r]);
        float ssum = 0.f;
        for (int r = 0; r < NR; ++r) { float ex = __expf(se[r] - m); se[r] = ex; ssum += ex; }
        float inv = 1.f / ssum;
        for (int r = 0; r < NR; ++r) se[r] *= inv;
    }
    __syncthreads();
    // awe: each thread owns 8 consecutive f (vector loads; r-order preserved)
    int f8 = tid << 3;                                   // 256*8 = 2048 = F
    const unsigned short* fb = feats_bf + (size_t)b * NR * F + f8;
    float s[8] = {};
    for (int r = 0; r < NR; ++r) {
        bf16x8 v = *(const bf16x8*)(fb + (size_t)r * F);
        float a = se[r];
#pragma unroll
        for (int q = 0; q < 8; ++q)
            s[q] += a * bf2f(((const unsigned short*)&v)[q]);
    }
    union { unsigned short u[8]; uint4 v4; } pk;
#pragma unroll
    for (int q = 0; q < 8; ++q) pk.u[q] = f2bf(s[q]);
    *(uint4*)(xlg + (size_t)b * 4096 + f8) = pk.v4;
}

// ---------------------------------------------------------------------------
extern "C" void kernel_launch(void* const* d_in, const int* in_sizes, int n_in,
                              void* d_out, int out_size, void* d_ws, size_t ws_size,
                              hipStream_t stream)
{
    const float* feats     = (const float*)d_in[0];
    const int*   sequences = (const int*)d_in[1];
    const int*   sizes     = (const int*)d_in[2];
    const float* emb       = (const float*)d_in[3];
    const float* td_wi = (const float*)d_in[4];
    const float* td_wh = (const float*)d_in[5];
    const float* td_bi = (const float*)d_in[6];
    const float* td_bh = (const float*)d_in[7];
    const float* lg_wi = (const float*)d_in[8];
    const float* lg_wh = (const float*)d_in[9];
    const float* lg_bi = (const float*)d_in[10];
    const float* lg_bh = (const float*)d_in[11];
    const float* ar_wi = (const float*)d_in[12];
    const float* ar_wh = (const float*)d_in[13];
    const float* ar_bi = (const float*)d_in[14];
    const float* ar_bh = (const float*)d_in[15];
    const float* arl_w = (const float*)d_in[16];
    const float* arl_b = (const float*)d_in[17];
    const float* out_w = (const float*)d_in[18];
    const float* out_b = (const float*)d_in[19];
    const float* af_w  = (const float*)d_in[20];
    const float* af_b  = (const float*)d_in[21];
    const float* ad_w  = (const float*)d_in[22];
    const float* ad_b  = (const float*)d_in[23];
    const float* aw_w  = (const float*)d_in[24];
    const float* aw_b  = (const float*)d_in[25];
    float* out = (float*)d_out;

    // ---- workspace carve (floats; every region multiple of 4 floats) ----
    float* ws = (float*)d_ws;
    size_t off = 0;
    auto alloc = [&](size_t n) { float* p = ws + off; off += n; return p; };
    // zero region: 6 f32 states + xtd + xlg + xar (contiguous)
    float* h1   = alloc((size_t)BD);
    float* c1   = alloc((size_t)BD);
    float* h2   = alloc((size_t)BD);
    float* c2   = alloc((size_t)BD);
    float* arh  = alloc((size_t)BD);
    float* arc  = alloc((size_t)BD);
    unsigned short* xtd = (unsigned short*)alloc((size_t)B * 5120 / 2);
    unsigned short* xlg = (unsigned short*)alloc((size_t)B * 4096 / 2);
    unsigned short* xar = (unsigned short*)alloc((size_t)B * 2048 / 2);
    int zero_n = 6 * BD + (B * 5120 + B * 4096 + B * 2048) / 2;  // 1,507,328
    // rest
    float* h1a       = alloc((size_t)B * A_DIM);
    float* prevh_all = alloc((size_t)(TD - 1) * BD);     // f32 h1 history (t=1..18)
    float* img_att   = alloc((size_t)B * NR * A_DIM);
    float* bias_td   = alloc(4096);
    float* bias_lg   = alloc(4096);
    float* bias_comb = alloc(5120);
    unsigned short* embs_bf  = (unsigned short*)alloc((size_t)B * TD * E / 2);
    unsigned short* feats_bf = (unsigned short*)alloc((size_t)B * NR * F / 2);
    unsigned short* Hout     = (unsigned short*)alloc((size_t)TD * BD / 2);       // h2 history
    unsigned short* Arout    = (unsigned short*)alloc((size_t)(TD - 1) * BD / 2); // arh history
    unsigned short* Wtd  = (unsigned short*)alloc((size_t)4096 * 5120 / 2);
    unsigned short* Wlg  = (unsigned short*)alloc((size_t)4096 * 4096 / 2);
    unsigned short* Wcomb = (unsigned short*)alloc((size_t)5120 * 2048 / 2);  // [War-il | Wad-pad]
    unsigned short* Wout = (unsigned short*)alloc((size_t)V * 1024 / 2);
    unsigned short* Warl = (unsigned short*)alloc((size_t)1024 * 1024 / 2);
    unsigned short* Waf  = (unsigned short*)alloc((size_t)1024 * 2048 / 2);
    int* ip     = (int*)(ws + off);
    int* order  = ip; ip += B;
    int* active = ip; ip += TD + 1;
    int* seqs_s = ip; ip += B * T;

    float* loss_ptr = out + (size_t)B * TD * V + B * T + B;

    // ---- prologue ----
    k_sort_init<<<1, B, 0, stream>>>(sizes, sequences, order, active, seqs_s, out);
    k_zero<<<(zero_n + 255) / 256, 256, 0, stream>>>(h1, zero_n);
    k_favg<<<1024, 256, 0, stream>>>(feats, order, xtd);
    k_emb2bf<<<(B * TD * 128 + 255) / 256, 256, 0, stream>>>(emb, seqs_s, embs_bf);
    k_feats2bf<<<4608, 256, 0, stream>>>(feats, order, feats_bf);
    k_w2bf<<<10240, 256, 0, stream>>>(td_wi, 4096, td_wh, 1024, Wtd, (long)4096 * 640, 1);
    k_w2bf<<<8192, 256, 0, stream>>>(lg_wi, 3072, lg_wh, 1024, Wlg, (long)4096 * 512, 1);
    k_w2bf<<<4096, 256, 0, stream>>>(ar_wi, 1024, ar_wh, 1024, Wcomb, (long)4096 * 256, 1);
    k_w2bf<<<1024, 256, 0, stream>>>(ad_w, 1024, nullptr, 1024,
                                     Wcomb + (size_t)4096 * 2048, (long)1024 * 256, 0);
    k_w2bf<<<5000, 256, 0, stream>>>(out_w, 1024, nullptr, 0, Wout, (long)V * 128, 0);
    k_w2bf<<<512, 256, 0, stream>>>(arl_w, 1024, nullptr, 0, Warl, (long)1024 * 128, 0);
    k_w2bf<<<1024, 256, 0, stream>>>(af_w, 2048, nullptr, 0, Waf, (long)1024 * 256, 0);
    k_biasint<<<16, 256, 0, stream>>>(td_bi, td_bh, nullptr, bias_td, 4096);
    k_biasint<<<16, 256, 0, stream>>>(lg_bi, lg_bh, nullptr, bias_lg, 4096);
    k_biasint<<<20, 256, 0, stream>>>(ar_bi, ar_bh, ad_b, bias_comb, 5120);
    // img_att = feats_bf @ Waf^T + af_b   [4608 x 1024]
    k_gemm<<<dim3(32, 36), 256, 0, stream>>>(
        feats_bf, 2048, Waf, 2048, af_b,
        img_att, 1024, 1024, 0, nullptr, nullptr, nullptr);
    k_embslot<<<64, 256, 0, stream>>>(embs_bf, xtd, 0);   // emb slot for t=0

    // ---- timestep loop (4 dispatches each) ----
    for (int t = 0; t < TD; ++t) {
        const int* actp = active + t;
        // top-down LSTM: gates GEMM + fused pointwise
        k_gemm_lstm<<<dim3(128), 256, 0, stream>>>(
            xtd, 5120, Wtd, 5120, bias_td, 4096, 4096,
            h1, c1, actp,
            (t > 0) ? prevh_all + (size_t)(t - 1) * BD : nullptr,
            xtd + 4096, 5120, xlg + 2048, 4096, xar, 2048,
            nullptr, nullptr, nullptr, 0);
        // combined ARNet gates (fused lstm) + attention projection (h1a store)
        k_gemm_lstm<<<dim3(160), 256, 0, stream>>>(
            xar, 2048, Wcomb, 2048, bias_comb, 4096, 5120,
            arh, arc, actp, nullptr,
            xar + 1024, 2048,
            (t > 0) ? Arout + (size_t)(t - 1) * BD : (unsigned short*)nullptr, 1024,
            nullptr, 0,
            h1a, nullptr, nullptr, 0);
        k_attn<<<B, 256, 0, stream>>>(h1a, 1024, img_att, aw_w, aw_b,
                                      feats_bf, xlg);
        // language LSTM: gates GEMM + fused pointwise + h2 history + emb prefetch
        k_gemm_lstm<<<dim3(128), 256, 0, stream>>>(
            xlg, 4096, Wlg, 4096, bias_lg, 4096, 4096,
            h2, c2, actp, nullptr,
            xtd, 5120, xlg + 3072, 4096, Hout + (size_t)t * BD, 1024,
            nullptr,
            (t + 1 < TD) ? embs_bf : (const unsigned short*)nullptr, xtd, t + 1);
    }

    // ---- deferred batched GEMMs ----
    // ARNet loss over t=1..18: (Arout @ Warl^T + arl_b - prevh_all)^2 masked
    k_gemm<<<dim3(32, TD - 1), 256, 0, stream>>>(
        Arout, 1024, Warl, 1024, arl_b,
        nullptr, 0, 1024, 1, prevh_all, active + 1, loss_ptr);
    // preds for all timesteps: [19*128 x 1024] @ Wout^T -> out[b][t][v]
    // grid axes swapped (x = t, y = V-panel) for Wout L2 adjacency
    k_gemm<<<dim3(TD, (V + 31) / 32), 256, 0, stream>>>(
        Hout, 1024, Wout, 1024, out_b,
        out, 0, V, 3, nullptr, active, nullptr);
}